// Round 6
// baseline (2764.547 us; speedup 1.0000x reference)
//
#include <hip/hip_runtime.h>

// R6: single fused kernel, 16 blocks x 768 threads (12 waves):
//   waves 0-7  = SCAN (R5's proven 656 cy/step body, setprio(1)),
//   waves 8-11 = HELPER producers (setprio(0)): compute xp[t'] = Wih x[t'] (+bias
//                added scan-side) for THIS block's 16 batch rows, LEAD=64 steps
//                ahead, into a 128-slot ring in d_ws (512 KB/block, L2-resident).
// Same-CU producer/consumer: ordering via the shared per-step s_barrier (matched
// counts across divergent roles) + helper vmcnt drain; no cross-block sync, no
// cross-XCD coherence. Helper x prefetch depth = 4 steps covers HBM latency.
// This hides R5's serial 305 us prepass under the scan.

#define SEQ   4096
#define BATCH 256
#define DIN   64
#define DH    128
#define LEAD   64
#define RSLOTS 128
#define SLOT_BYTES 4096                      // 16 rows x 128 j x f16
#define RING_BYTES ((size_t)RSLOTS * SLOT_BYTES)

typedef _Float16 half8  __attribute__((ext_vector_type(8)));
typedef _Float16 half4v __attribute__((ext_vector_type(4)));
typedef _Float16 half2v __attribute__((ext_vector_type(2)));
typedef __fp16   fp16x2 __attribute__((ext_vector_type(2)));
typedef float    f32x4  __attribute__((ext_vector_type(4)));
typedef float    f32x2  __attribute__((ext_vector_type(2)));

union H2 { fp16x2 q; half2v h; unsigned int u; };

__device__ __forceinline__ float fast_tanh(float v) {
    float e = __builtin_amdgcn_exp2f(v * 2.88539008177792681472f);
    return 1.0f - 2.0f * __builtin_amdgcn_rcpf(e + 1.0f);
}

__device__ __forceinline__ int hoff(int b, int j) {
    return b * 256 + ((((j >> 3) ^ b) & 15) << 4) + (j & 7) * 2;
}

__device__ __forceinline__ half2v pk(float a, float b) {
    H2 u; u.q = __builtin_amdgcn_cvt_pkrtz(a, b);
    return u.h;
}

__device__ __forceinline__ half8 cvt8(f32x4 a, f32x4 b) {
    half2v p0 = pk(a[0], a[1]);
    half2v p1 = pk(a[2], a[3]);
    half2v p2 = pk(b[0], b[1]);
    half2v p3 = pk(b[2], b[3]);
    half8 r;
    r[0] = p0[0]; r[1] = p0[1]; r[2] = p1[0]; r[3] = p1[1];
    r[4] = p2[0]; r[5] = p2[1]; r[6] = p3[0]; r[7] = p3[1];
    return r;
}

__device__ __forceinline__ half4v pack4(f32x4 a) {
    half2v q0 = pk(a[0], a[1]);
    half2v q1 = pk(a[2], a[3]);
    half4v r;
    r[0] = q0[0]; r[1] = q0[1]; r[2] = q1[0]; r[3] = q1[1];
    return r;
}

__device__ __forceinline__ f32x4 cvt4f(half4v v) {
    f32x4 r;
    r[0] = (float)v[0]; r[1] = (float)v[1];
    r[2] = (float)v[2]; r[3] = (float)v[3];
    return r;
}

struct XSlot { f32x4 v0, v1, v2, v3; };

#define XLOAD(slot, p_) do {                                           \
        (slot).v0 = *(const f32x4*)(p_);                               \
        (slot).v1 = *(const f32x4*)((p_) + 4);                         \
        (slot).v2 = *(const f32x4*)((p_) + 32);                        \
        (slot).v3 = *(const f32x4*)((p_) + 36);                        \
    } while (0)

__launch_bounds__(768, 3)
__global__ void rnn_fused_all(const float* __restrict__ x,     // [SEQ][BATCH][DIN]
                              const float* __restrict__ Wih,   // [DH][DIN]
                              const float* __restrict__ bih,   // [DH]
                              const float* __restrict__ Whh,   // [DH][DH]
                              const float* __restrict__ bhh,   // [DH]
                              float* __restrict__ out,         // [BATCH][DH]
                              char* __restrict__ ring_all)     // 16 x RING_BYTES
{
    __shared__ __align__(16) char hbuf[8192];   // 2 x swizzled [16][128] f16

    const int tid   = threadIdx.x;
    const int wave  = tid >> 6;
    const int lane  = tid & 63;
    const int lb    = lane & 15;
    const int lg    = lane >> 4;
    const int bbase = blockIdx.x << 4;
    char* ring = ring_all + (size_t)blockIdx.x * RING_BYTES;

    if (wave < 8) {
        // ================= SCAN ROLE (R5 body, xp from ring) =================
        __builtin_amdgcn_s_setprio(1);
        const int jbase = wave << 4;

        half8 Ahh[4];
        #pragma unroll
        for (int kt = 0; kt < 4; ++kt) {
            const float* wr = Whh + (jbase + lb) * DH + kt * 32 + (lg << 3);
            half8 f;
            #pragma unroll
            for (int i = 0; i < 8; ++i) f[i] = (_Float16)wr[i];
            Ahh[kt] = f;
        }
        f32x4 biasv;
        #pragma unroll
        for (int r = 0; r < 4; ++r) {
            int j = jbase + (lg << 2) + r;
            biasv[r] = bih[j] + bhh[j];
        }

        const int woff  = hoff(lb, jbase + (lg << 2));
        const int roff0 = hoff(lb, 0 * 32 + (lg << 3));
        const int roff1 = hoff(lb, 1 * 32 + (lg << 3));
        const int roff2 = hoff(lb, 2 * 32 + (lg << 3));
        const int roff3 = hoff(lb, 3 * 32 + (lg << 3));
        const int rdoff = lb * 256 + ((jbase + (lg << 2)) << 1);   // byte off in slot

        half8 hf0, hf1, hf2, hf3;
        {
            half8 z;
            #pragma unroll
            for (int i = 0; i < 8; ++i) z[i] = (_Float16)0.0f;
            hf0 = hf1 = hf2 = hf3 = z;   // h_0 = 0
        }
        f32x4 ci = {0.0f, 0.0f, 0.0f, 0.0f};
        half4v xq1 = {};

        #pragma unroll 2
        for (int s = -LEAD; s < SEQ - 1; ++s) {
            if (s >= 0) {
                const int t = s;
                char* hb = hbuf + (((t + 1) & 1) << 12);

                f32x4 zz = {0.0f, 0.0f, 0.0f, 0.0f};
                f32x4 acc1, acc2;
                acc1 = __builtin_amdgcn_mfma_f32_16x16x32_f16(Ahh[0], hf0, ci,   0, 0, 0);
                acc2 = __builtin_amdgcn_mfma_f32_16x16x32_f16(Ahh[2], hf2, zz,   0, 0, 0);
                acc1 = __builtin_amdgcn_mfma_f32_16x16x32_f16(Ahh[1], hf1, acc1, 0, 0, 0);
                acc2 = __builtin_amdgcn_mfma_f32_16x16x32_f16(Ahh[3], hf3, acc2, 0, 0, 0);

                // prefetch xp[t+2] from ring (written by helpers 62 steps ago)
                const int tn = (t + 2 < SEQ) ? t + 2 : SEQ - 1;
                half4v xnew = *(const half4v*)(ring + ((tn & (RSLOTS - 1)) * SLOT_BYTES) + rdoff);

                f32x4 rA;
                #pragma unroll
                for (int r = 0; r < 4; ++r) rA[r] = fast_tanh(acc1[r] + acc2[r]);
                *(half4v*)(hb + woff) = pack4(rA);

                // rotate xp pipeline: ci <- xp[t+1] + bias (off critical path)
                ci = cvt4f(xq1) + biasv;
                xq1 = xnew;

                asm volatile("s_waitcnt lgkmcnt(0)" ::: "memory");
                __builtin_amdgcn_s_barrier();
                asm volatile("" ::: "memory");

                hf0 = *(const half8*)(hb + roff0);
                hf2 = *(const half8*)(hb + roff2);
                hf1 = *(const half8*)(hb + roff1);
                hf3 = *(const half8*)(hb + roff3);
            } else {
                // warmup: helpers fill the ring; scan just paces the barrier
                __builtin_amdgcn_s_barrier();
                asm volatile("" ::: "memory");
                if (s == -1) {
                    half4v x0 = *(const half4v*)(ring + 0 * SLOT_BYTES + rdoff);
                    xq1       = *(const half4v*)(ring + 1 * SLOT_BYTES + rdoff);
                    ci = cvt4f(x0) + biasv;
                }
            }
        }

        // epilogue: t = SEQ-1 -> h_final -> out (f32)
        {
            f32x4 zz = {0.0f, 0.0f, 0.0f, 0.0f};
            f32x4 acc1, acc2;
            acc1 = __builtin_amdgcn_mfma_f32_16x16x32_f16(Ahh[0], hf0, ci,   0, 0, 0);
            acc2 = __builtin_amdgcn_mfma_f32_16x16x32_f16(Ahh[2], hf2, zz,   0, 0, 0);
            acc1 = __builtin_amdgcn_mfma_f32_16x16x32_f16(Ahh[1], hf1, acc1, 0, 0, 0);
            acc2 = __builtin_amdgcn_mfma_f32_16x16x32_f16(Ahh[3], hf3, acc2, 0, 0, 0);
            f32x4 rA;
            #pragma unroll
            for (int r = 0; r < 4; ++r) rA[r] = fast_tanh(acc1[r] + acc2[r]);
            *(f32x4*)(out + (size_t)(bbase + lb) * DH + jbase + (lg << 2)) = rA;
        }
    } else {
        // ================= HELPER ROLE: produce xp ring =================
        __builtin_amdgcn_s_setprio(0);
        const int h = wave - 8;   // 0..3; handles t' == h (mod 4)

        half8 Aih[8][2];
        #pragma unroll
        for (int s8 = 0; s8 < 8; ++s8) {
            #pragma unroll
            for (int kt = 0; kt < 2; ++kt) {
                const float* wr = Wih + (s8 * 16 + lb) * DIN + kt * 32 + (lg << 3);
                half8 f;
                #pragma unroll
                for (int i = 0; i < 8; ++i) f[i] = (_Float16)wr[i];
                Aih[s8][kt] = f;
            }
        }

        // prefetch x for first chunk t' = h
        XSlot xs;
        XLOAD(xs, x + ((size_t)h * BATCH + bbase + lb) * DIN + (lg << 3));

        for (int s = -LEAD; s < SEQ - 1; ++s) {
            const int tp = s + LEAD;
            if ((tp & 3) == h && tp < SEQ) {
                half8 xf0 = cvt8(xs.v0, xs.v1);
                half8 xf1 = cvt8(xs.v2, xs.v3);
                char* wp = ring + ((tp & (RSLOTS - 1)) * SLOT_BYTES) + lb * 256 + (lg << 3);
                f32x4 zz = {0.0f, 0.0f, 0.0f, 0.0f};
                #pragma unroll
                for (int s8 = 0; s8 < 8; ++s8) {
                    f32x4 a;
                    a = __builtin_amdgcn_mfma_f32_16x16x32_f16(Aih[s8][0], xf0, zz, 0, 0, 0);
                    a = __builtin_amdgcn_mfma_f32_16x16x32_f16(Aih[s8][1], xf1, a,  0, 0, 0);
                    *(half4v*)(wp + s8 * 32) = pack4(a);   // stores issued before next loads
                }
                // prefetch x for next chunk (4 steps ~ 2600 cy of slack)
                const int tl = tp + 4;
                if (tl < SEQ) {
                    XLOAD(xs, x + ((size_t)tl * BATCH + bbase + lb) * DIN + (lg << 3));
                }
                // drain the 8 stores (older than the 4 prefetch loads)
                asm volatile("s_waitcnt vmcnt(4)" ::: "memory");
            }
            __builtin_amdgcn_s_barrier();
            asm volatile("" ::: "memory");
        }
        // matched barrier count with scan loop; nothing after
    }
}

// ---------------------------------------------------------------------------
// Fallback (R2 fused, proven 1768 us) if d_ws is too small for the ring.
// ---------------------------------------------------------------------------
#define XSTEP (BATCH * DIN)
__device__ __forceinline__ int hoffc(int b, int chunk, int lo) {
    return b * 256 + ((chunk ^ b) << 4) + lo;
}
__device__ __forceinline__ int xoff_lds(int b, int chunk, int lo) {
    return b * 128 + (((chunk ^ (b & 7)) << 4) + lo);
}

__launch_bounds__(512, 1)
__global__ void rnn_fused_scan_r2(const float* __restrict__ x,
                                  const float* __restrict__ Wih,
                                  const float* __restrict__ bih,
                                  const float* __restrict__ Whh,
                                  const float* __restrict__ bhh,
                                  float* __restrict__ out)
{
    __shared__ __align__(16) char lds[12288];
    char* hbuf = lds;
    char* xbuf = lds + 8192;

    const int tid   = threadIdx.x;
    const int wave  = tid >> 6;
    const int lane  = tid & 63;
    const int lb    = lane & 15;
    const int lg    = lane >> 4;
    const int bbase = blockIdx.x << 4;
    const int jbase = wave << 4;

    half8 Ahh[4], Aih[2];
    #pragma unroll
    for (int kt = 0; kt < 4; ++kt) {
        const float* wr = Whh + (jbase + lb) * DH + kt * 32 + lg * 8;
        half8 f;
        #pragma unroll
        for (int i = 0; i < 8; ++i) f[i] = (_Float16)wr[i];
        Ahh[kt] = f;
    }
    #pragma unroll
    for (int kt = 0; kt < 2; ++kt) {
        const float* wr = Wih + (jbase + lb) * DIN + kt * 32 + lg * 8;
        half8 f;
        #pragma unroll
        for (int i = 0; i < 8; ++i) f[i] = (_Float16)wr[i];
        Aih[kt] = f;
    }
    f32x4 bias;
    #pragma unroll
    for (int r = 0; r < 4; ++r) {
        int j = jbase + lg * 4 + r;
        bias[r] = bih[j] + bhh[j];
    }

    const int bx = tid >> 5;
    const int kx = (tid & 31) << 1;
    const float* xlane = x + (size_t)(bbase + bx) * DIN + kx;

    f32x2 r0  = *(const f32x2*)(xlane + 0 * (size_t)XSTEP);
    f32x2 rx0 = *(const f32x2*)(xlane + 1 * (size_t)XSTEP);
    f32x2 rx1 = *(const f32x2*)(xlane + 2 * (size_t)XSTEP);
    f32x2 rx2 = *(const f32x2*)(xlane + 3 * (size_t)XSTEP);
    {
        half2v p; p[0] = (_Float16)r0[0]; p[1] = (_Float16)r0[1];
        *(half2v*)(xbuf + xoff_lds(bx, kx >> 3, (kx & 7) * 2)) = p;
    }
    const float* xload = xlane + 4 * (size_t)XSTEP;

    half8 hf0, hf1, hf2, hf3, xf0, xf1;
    {
        half8 z;
        #pragma unroll
        for (int i = 0; i < 8; ++i) z[i] = (_Float16)0.0f;
        hf0 = hf1 = hf2 = hf3 = z;
    }

    asm volatile("s_waitcnt lgkmcnt(0)" ::: "memory");
    __builtin_amdgcn_s_barrier();
    asm volatile("" ::: "memory");
    xf0 = *(const half8*)(xbuf + xoff_lds(lb, 0 * 4 + lg, 0));
    xf1 = *(const half8*)(xbuf + xoff_lds(lb, 1 * 4 + lg, 0));

    f32x4 acc_ih;
    acc_ih = __builtin_amdgcn_mfma_f32_16x16x32_f16(Aih[0], xf0, bias,   0, 0, 0);
    acc_ih = __builtin_amdgcn_mfma_f32_16x16x32_f16(Aih[1], xf1, acc_ih, 0, 0, 0);

    #pragma unroll 2
    for (int t = 0; t < SEQ - 1; ++t) {
        f32x4 zz = {0.0f, 0.0f, 0.0f, 0.0f};
        f32x4 acc1, acc2;
        acc1 = __builtin_amdgcn_mfma_f32_16x16x32_f16(Ahh[0], hf0, acc_ih, 0, 0, 0);
        acc2 = __builtin_amdgcn_mfma_f32_16x16x32_f16(Ahh[2], hf2, zz,     0, 0, 0);
        acc1 = __builtin_amdgcn_mfma_f32_16x16x32_f16(Ahh[1], hf1, acc1,   0, 0, 0);
        acc2 = __builtin_amdgcn_mfma_f32_16x16x32_f16(Ahh[3], hf3, acc2,   0, 0, 0);

        const int nb = (t + 1) & 1;
        {
            half2v p; p[0] = (_Float16)rx0[0]; p[1] = (_Float16)rx0[1];
            *(half2v*)(xbuf + nb * 2048 + xoff_lds(bx, kx >> 3, (kx & 7) * 2)) = p;
        }
        rx0 = rx1; rx1 = rx2;
        rx2 = *(const f32x2*)xload;
        if (t + 5 < SEQ) xload += XSTEP;

        f32x4 hv;
        #pragma unroll
        for (int r = 0; r < 4; ++r) hv[r] = fast_tanh(acc1[r] + acc2[r]);
        {
            half4v p;
            #pragma unroll
            for (int r = 0; r < 4; ++r) p[r] = (_Float16)hv[r];
            *(half4v*)(hbuf + nb * 4096 + hoffc(lb, (wave << 1) + (lg >> 1), (lg & 1) * 8)) = p;
        }

        asm volatile("s_waitcnt lgkmcnt(0)" ::: "memory");
        __builtin_amdgcn_s_barrier();
        asm volatile("" ::: "memory");

        hf0 = *(const half8*)(hbuf + nb * 4096 + hoffc(lb, 0 * 4 + lg, 0));
        hf2 = *(const half8*)(hbuf + nb * 4096 + hoffc(lb, 2 * 4 + lg, 0));
        hf1 = *(const half8*)(hbuf + nb * 4096 + hoffc(lb, 1 * 4 + lg, 0));
        hf3 = *(const half8*)(hbuf + nb * 4096 + hoffc(lb, 3 * 4 + lg, 0));
        xf0 = *(const half8*)(xbuf + nb * 2048 + xoff_lds(lb, 0 * 4 + lg, 0));
        xf1 = *(const half8*)(xbuf + nb * 2048 + xoff_lds(lb, 1 * 4 + lg, 0));

        acc_ih = __builtin_amdgcn_mfma_f32_16x16x32_f16(Aih[0], xf0, bias,   0, 0, 0);
        acc_ih = __builtin_amdgcn_mfma_f32_16x16x32_f16(Aih[1], xf1, acc_ih, 0, 0, 0);
    }

    {
        f32x4 zz = {0.0f, 0.0f, 0.0f, 0.0f};
        f32x4 acc1, acc2;
        acc1 = __builtin_amdgcn_mfma_f32_16x16x32_f16(Ahh[0], hf0, acc_ih, 0, 0, 0);
        acc2 = __builtin_amdgcn_mfma_f32_16x16x32_f16(Ahh[2], hf2, zz,     0, 0, 0);
        acc1 = __builtin_amdgcn_mfma_f32_16x16x32_f16(Ahh[1], hf1, acc1,   0, 0, 0);
        acc2 = __builtin_amdgcn_mfma_f32_16x16x32_f16(Ahh[3], hf3, acc2,   0, 0, 0);
        f32x4 res;
        #pragma unroll
        for (int r = 0; r < 4; ++r) res[r] = fast_tanh(acc1[r] + acc2[r]);
        *(f32x4*)(out + (size_t)(bbase + lb) * DH + jbase + (lg << 2)) = res;
    }
}

extern "C" void kernel_launch(void* const* d_in, const int* in_sizes, int n_in,
                              void* d_out, int out_size, void* d_ws, size_t ws_size,
                              hipStream_t stream) {
    const float* x   = (const float*)d_in[0];
    const float* Wih = (const float*)d_in[1];
    const float* bih = (const float*)d_in[2];
    const float* Whh = (const float*)d_in[3];
    const float* bhh = (const float*)d_in[4];
    float* out = (float*)d_out;

    const size_t need = 16 * RING_BYTES;   // 8 MB
    if (ws_size >= need) {
        rnn_fused_all<<<16, 768, 0, stream>>>(x, Wih, bih, Whh, bhh, out, (char*)d_ws);
    } else {
        rnn_fused_scan_r2<<<16, 512, 0, stream>>>(x, Wih, bih, Whh, bhh, out);
    }
}

// Round 7
// 1416.199 us; speedup vs baseline: 1.9521x; 1.9521x over previous
//
#include <hip/hip_runtime.h>

// R7: two-kernel scheme (R5 structure, champion 1424 us).
//  (1) rnn_prepass v2: xp[t][b][j] = fp16(W_ih x[t][b] + b_ih + b_hh).
//      Same MFMA core as R5's prepass, but the output tile is staged in
//      wave-private LDS (XOR-swizzled) and stored as 4x 1KB coalesced
//      global_store_dwordx4 bursts (R5 scattered 8B pieces at 50% line
//      efficiency over 256 MB -> the 305us prepass cost).
//  (2) rnn_scan_xp: BYTE-IDENTICAL to R5's scan (656 cy/step, at its
//      structural LDS-pipe floor; R6 proved helpers must stay out of it).
//  Fallback to the proven R2 fused kernel if ws_size < 256 MB.

#define SEQ   4096
#define BATCH 256
#define DIN   64
#define DH    128
#define XSTEP (BATCH * DIN)

typedef _Float16 half8  __attribute__((ext_vector_type(8)));
typedef _Float16 half4v __attribute__((ext_vector_type(4)));
typedef _Float16 half2v __attribute__((ext_vector_type(2)));
typedef __fp16   fp16x2 __attribute__((ext_vector_type(2)));
typedef float    f32x4  __attribute__((ext_vector_type(4)));
typedef float    f32x2  __attribute__((ext_vector_type(2)));

union H2 { fp16x2 q; half2v h; unsigned int u; };

// tanh(x) = 1 - 2/(1 + e^{2x}); overflow-free for all finite x.
__device__ __forceinline__ float fast_tanh(float v) {
    float e = __builtin_amdgcn_exp2f(v * 2.88539008177792681472f);
    return 1.0f - 2.0f * __builtin_amdgcn_rcpf(e + 1.0f);
}

__device__ __forceinline__ half2v pk(float a, float b) {
    H2 u; u.q = __builtin_amdgcn_cvt_pkrtz(a, b);
    return u.h;
}

__device__ __forceinline__ half8 cvt8(f32x4 a, f32x4 b) {
    half2v p0 = pk(a[0], a[1]);
    half2v p1 = pk(a[2], a[3]);
    half2v p2 = pk(b[0], b[1]);
    half2v p3 = pk(b[2], b[3]);
    half8 r;
    r[0] = p0[0]; r[1] = p0[1]; r[2] = p1[0]; r[3] = p1[1];
    r[4] = p2[0]; r[5] = p2[1]; r[6] = p3[0]; r[7] = p3[1];
    return r;
}

__device__ __forceinline__ half4v pack4(f32x4 a) {
    half2v q0 = pk(a[0], a[1]);
    half2v q1 = pk(a[2], a[3]);
    half4v r;
    r[0] = q0[0]; r[1] = q0[1]; r[2] = q1[0]; r[3] = q1[1];
    return r;
}

__device__ __forceinline__ f32x4 cvt4f(half4v v) {
    f32x4 r;
    r[0] = (float)v[0]; r[1] = (float)v[1];
    r[2] = (float)v[2]; r[3] = (float)v[3];
    return r;
}

// byte offset of h[b][j] (f16) in a [16][128] tile; 16B-chunk XOR swizzle by b.
__device__ __forceinline__ int hoff(int b, int j) {
    return b * 256 + ((((j >> 3) ^ b) & 15) << 4) + (j & 7) * 2;
}

// ---------------------------------------------------------------------------
// Kernel 1: prepass GEMM, v2 with LDS-staged coalesced stores.
// row = t*BATCH + b (1,048,576 rows). Block = 4 waves x 16 rows; wave does
// 16 rows x 128 j = 16 MFMA (8 j-subtiles x K64), stages the f16 tile in
// wave-private LDS, then 4x 1KB coalesced global stores.
// ---------------------------------------------------------------------------
__launch_bounds__(256)
__global__ void rnn_prepass(const float* __restrict__ x,     // [SEQ*BATCH][DIN]
                            const float* __restrict__ Wih,   // [DH][DIN]
                            const float* __restrict__ bih,   // [DH]
                            const float* __restrict__ bhh,   // [DH]
                            _Float16* __restrict__ xp)       // [SEQ*BATCH][DH]
{
    __shared__ __align__(16) char sbuf[16384];   // 4 waves x [16 rows][256 B]

    const int tid  = threadIdx.x;
    const int w    = tid >> 6;
    const int lane = tid & 63;
    const int lb   = lane & 15;
    const int lg   = lane >> 4;
    const int rowbase = blockIdx.x * 64 + w * 16;
    char* tile = sbuf + w * 4096;

    // A-frags: Wih for 8 j-subtiles x 2 k-halves
    half8 A[8][2];
    #pragma unroll
    for (int s = 0; s < 8; ++s) {
        #pragma unroll
        for (int kt = 0; kt < 2; ++kt) {
            const float* wr = Wih + (s * 16 + lb) * DIN + kt * 32 + lg * 8;
            half8 f;
            #pragma unroll
            for (int i = 0; i < 8; ++i) f[i] = (_Float16)wr[i];
            A[s][kt] = f;
        }
    }
    f32x4 bias[8];
    #pragma unroll
    for (int s = 0; s < 8; ++s)
        #pragma unroll
        for (int r = 0; r < 4; ++r) {
            int j = s * 16 + lg * 4 + r;
            bias[s][r] = bih[j] + bhh[j];
        }

    // B-frags: x row (rowbase+lb), k = kt*32 + lg*8 .. +7
    const float* xr = x + (size_t)(rowbase + lb) * DIN + lg * 8;
    half8 xf0 = cvt8(*(const f32x4*)(xr),      *(const f32x4*)(xr + 4));
    half8 xf1 = cvt8(*(const f32x4*)(xr + 32), *(const f32x4*)(xr + 36));

    // MFMA -> pack -> swizzled LDS stage.
    // D elem (lane, s, r) = xp[row=rowbase+lb][j = s*16 + lg*4 + r].
    // Row byte offset of the 8B piece = s*32 + lg*8; 16B-chunk = s*2+(lg>>1),
    // lo = (lg&1)*8; swizzle chunk ^ lb.
    #pragma unroll
    for (int s = 0; s < 8; ++s) {
        f32x4 acc;
        acc = __builtin_amdgcn_mfma_f32_16x16x32_f16(A[s][0], xf0, bias[s], 0, 0, 0);
        acc = __builtin_amdgcn_mfma_f32_16x16x32_f16(A[s][1], xf1, acc,     0, 0, 0);
        const int chunk = s * 2 + (lg >> 1);
        const int off   = lb * 256 + (((chunk ^ lb) & 15) << 4) + (lg & 1) * 8;
        *(half4v*)(tile + off) = pack4(acc);
    }

    // own-wave writes -> own-wave reads: lgkm drain, no barrier needed
    asm volatile("s_waitcnt lgkmcnt(0)" ::: "memory");

    // 4x coalesced 1KB stores: instr q covers rows q*4..q*4+3 fully.
    char* dst = (char*)(xp + (size_t)rowbase * DH);
    #pragma unroll
    for (int q = 0; q < 4; ++q) {
        const int row = q * 4 + (lane >> 4);
        const int c   = lane & 15;
        f32x4 v = *(const f32x4*)(tile + row * 256 + (((c ^ row) & 15) << 4));
        *(f32x4*)(dst + row * 256 + c * 16) = v;
    }
}

// ---------------------------------------------------------------------------
// Kernel 2: the scan. BYTE-IDENTICAL to R5 (proven 1119 us, 656 cy/step).
// ---------------------------------------------------------------------------
__launch_bounds__(512, 1)
__global__ void rnn_scan_xp(const _Float16* __restrict__ xp,  // [SEQ][BATCH][DH]
                            const float* __restrict__ Whh,    // [DH][DH]
                            float* __restrict__ out)          // [BATCH][DH]
{
    __shared__ __align__(16) char hbuf[8192];   // 2 x swizzled [16][128] f16

    const int tid   = threadIdx.x;
    const int wave  = tid >> 6;
    const int lane  = tid & 63;
    const int lb    = lane & 15;
    const int lg    = lane >> 4;
    const int bbase = blockIdx.x << 4;
    const int jbase = wave << 4;

    // persistent W_hh A-frags (K=128 -> 4)
    half8 Ahh[4];
    #pragma unroll
    for (int kt = 0; kt < 4; ++kt) {
        const float* wr = Whh + (jbase + lb) * DH + kt * 32 + lg * 8;
        half8 f;
        #pragma unroll
        for (int i = 0; i < 8; ++i) f[i] = (_Float16)wr[i];
        Ahh[kt] = f;
    }

    // xp ring: per lane 4 f16 = xp[t][bbase+lb][jbase + lg*4 .. +3]
    const _Float16* xpp = xp + (size_t)(bbase + lb) * DH + jbase + (lg << 2);
    const size_t XPS = (size_t)BATCH * DH;

    half4v xq1, xq2, xq3;
    f32x4 ci;   // f32 xp[t], C-in of chain 1
    {
        half4v x0 = *(const half4v*)(xpp);
        xq1 = *(const half4v*)(xpp + 1 * XPS);
        xq2 = *(const half4v*)(xpp + 2 * XPS);
        xq3 = *(const half4v*)(xpp + 3 * XPS);
        ci = cvt4f(x0);
    }
    const _Float16* xload = xpp + 4 * XPS;   // -> xp[min(t+4, SEQ-1)]

    half8 hf0, hf1, hf2, hf3;
    {
        half8 z;
        #pragma unroll
        for (int i = 0; i < 8; ++i) z[i] = (_Float16)0.0f;
        hf0 = hf1 = hf2 = hf3 = z;   // h_0 = 0
    }

    const int woff  = hoff(lb, jbase + (lg << 2));
    const int roff0 = hoff(lb, 0 * 32 + (lg << 3));
    const int roff1 = hoff(lb, 1 * 32 + (lg << 3));
    const int roff2 = hoff(lb, 2 * 32 + (lg << 3));
    const int roff3 = hoff(lb, 3 * 32 + (lg << 3));

    #pragma unroll 2
    for (int t = 0; t < SEQ - 1; ++t) {
        const int nb = (t + 1) & 1;
        char* hb = hbuf + nb * 4096;

        // hh: 2 independent depth-2 chains; chain1 C-in = xp[t] (+bias folded in)
        f32x4 zz = {0.0f, 0.0f, 0.0f, 0.0f};
        f32x4 acc1, acc2;
        acc1 = __builtin_amdgcn_mfma_f32_16x16x32_f16(Ahh[0], hf0, ci,   0, 0, 0);
        acc2 = __builtin_amdgcn_mfma_f32_16x16x32_f16(Ahh[2], hf2, zz,   0, 0, 0);
        acc1 = __builtin_amdgcn_mfma_f32_16x16x32_f16(Ahh[1], hf1, acc1, 0, 0, 0);
        acc2 = __builtin_amdgcn_mfma_f32_16x16x32_f16(Ahh[3], hf3, acc2, 0, 0, 0);

        // prefetch xp[t+4] (clamped at tail; extra loads of last row unused)
        half4v xnew = *(const half4v*)xload;
        if (t + 5 < SEQ) xload += XPS;

        // h_{t+1} = tanh(z) -> fp16 -> LDS
        f32x4 rA;
        #pragma unroll
        for (int r = 0; r < 4; ++r) rA[r] = fast_tanh(acc1[r] + acc2[r]);
        *(half4v*)(hb + woff) = pack4(rA);

        // rotate ring; ci <- xp[t+1] (off critical path)
        ci = cvt4f(xq1);
        xq1 = xq2; xq2 = xq3; xq3 = xnew;

        // publish h_{t+1}; manual lgkm-only drain (no vmcnt -> xp loads stay in flight)
        asm volatile("s_waitcnt lgkmcnt(0)" ::: "memory");
        __builtin_amdgcn_s_barrier();
        asm volatile("" ::: "memory");

        hf0 = *(const half8*)(hb + roff0);
        hf2 = *(const half8*)(hb + roff2);
        hf1 = *(const half8*)(hb + roff1);
        hf3 = *(const half8*)(hb + roff3);
    }

    // epilogue: t = SEQ-1 -> h_final -> out (f32)
    {
        f32x4 zz = {0.0f, 0.0f, 0.0f, 0.0f};
        f32x4 acc1, acc2;
        acc1 = __builtin_amdgcn_mfma_f32_16x16x32_f16(Ahh[0], hf0, ci,   0, 0, 0);
        acc2 = __builtin_amdgcn_mfma_f32_16x16x32_f16(Ahh[2], hf2, zz,   0, 0, 0);
        acc1 = __builtin_amdgcn_mfma_f32_16x16x32_f16(Ahh[1], hf1, acc1, 0, 0, 0);
        acc2 = __builtin_amdgcn_mfma_f32_16x16x32_f16(Ahh[3], hf3, acc2, 0, 0, 0);
        f32x4 rA;
        #pragma unroll
        for (int r = 0; r < 4; ++r) rA[r] = fast_tanh(acc1[r] + acc2[r]);
        *(f32x4*)(out + (size_t)(bbase + lb) * DH + jbase + (lg << 2)) = rA;
    }
}

// ---------------------------------------------------------------------------
// Fallback (R2 fused, proven 1768 us) if d_ws is too small for xp.
// ---------------------------------------------------------------------------
__device__ __forceinline__ int hoffc(int b, int chunk, int lo) {
    return b * 256 + ((chunk ^ b) << 4) + lo;
}
__device__ __forceinline__ int xoff_lds(int b, int chunk, int lo) {
    return b * 128 + (((chunk ^ (b & 7)) << 4) + lo);
}

__launch_bounds__(512, 1)
__global__ void rnn_fused_scan_r2(const float* __restrict__ x,
                                  const float* __restrict__ Wih,
                                  const float* __restrict__ bih,
                                  const float* __restrict__ Whh,
                                  const float* __restrict__ bhh,
                                  float* __restrict__ out)
{
    __shared__ __align__(16) char lds[12288];
    char* hbuf = lds;
    char* xbuf = lds + 8192;

    const int tid   = threadIdx.x;
    const int wave  = tid >> 6;
    const int lane  = tid & 63;
    const int lb    = lane & 15;
    const int lg    = lane >> 4;
    const int bbase = blockIdx.x << 4;
    const int jbase = wave << 4;

    half8 Ahh[4], Aih[2];
    #pragma unroll
    for (int kt = 0; kt < 4; ++kt) {
        const float* wr = Whh + (jbase + lb) * DH + kt * 32 + lg * 8;
        half8 f;
        #pragma unroll
        for (int i = 0; i < 8; ++i) f[i] = (_Float16)wr[i];
        Ahh[kt] = f;
    }
    #pragma unroll
    for (int kt = 0; kt < 2; ++kt) {
        const float* wr = Wih + (jbase + lb) * DIN + kt * 32 + lg * 8;
        half8 f;
        #pragma unroll
        for (int i = 0; i < 8; ++i) f[i] = (_Float16)wr[i];
        Aih[kt] = f;
    }
    f32x4 bias;
    #pragma unroll
    for (int r = 0; r < 4; ++r) {
        int j = jbase + lg * 4 + r;
        bias[r] = bih[j] + bhh[j];
    }

    const int bx = tid >> 5;
    const int kx = (tid & 31) << 1;
    const float* xlane = x + (size_t)(bbase + bx) * DIN + kx;

    f32x2 r0  = *(const f32x2*)(xlane + 0 * (size_t)XSTEP);
    f32x2 rx0 = *(const f32x2*)(xlane + 1 * (size_t)XSTEP);
    f32x2 rx1 = *(const f32x2*)(xlane + 2 * (size_t)XSTEP);
    f32x2 rx2 = *(const f32x2*)(xlane + 3 * (size_t)XSTEP);
    {
        half2v p; p[0] = (_Float16)r0[0]; p[1] = (_Float16)r0[1];
        *(half2v*)(xbuf + xoff_lds(bx, kx >> 3, (kx & 7) * 2)) = p;
    }
    const float* xload = xlane + 4 * (size_t)XSTEP;

    half8 hf0, hf1, hf2, hf3, xf0, xf1;
    {
        half8 z;
        #pragma unroll
        for (int i = 0; i < 8; ++i) z[i] = (_Float16)0.0f;
        hf0 = hf1 = hf2 = hf3 = z;
    }

    asm volatile("s_waitcnt lgkmcnt(0)" ::: "memory");
    __builtin_amdgcn_s_barrier();
    asm volatile("" ::: "memory");
    xf0 = *(const half8*)(xbuf + xoff_lds(lb, 0 * 4 + lg, 0));
    xf1 = *(const half8*)(xbuf + xoff_lds(lb, 1 * 4 + lg, 0));

    f32x4 acc_ih;
    acc_ih = __builtin_amdgcn_mfma_f32_16x16x32_f16(Aih[0], xf0, bias,   0, 0, 0);
    acc_ih = __builtin_amdgcn_mfma_f32_16x16x32_f16(Aih[1], xf1, acc_ih, 0, 0, 0);

    #pragma unroll 2
    for (int t = 0; t < SEQ - 1; ++t) {
        f32x4 zz = {0.0f, 0.0f, 0.0f, 0.0f};
        f32x4 acc1, acc2;
        acc1 = __builtin_amdgcn_mfma_f32_16x16x32_f16(Ahh[0], hf0, acc_ih, 0, 0, 0);
        acc2 = __builtin_amdgcn_mfma_f32_16x16x32_f16(Ahh[2], hf2, zz,     0, 0, 0);
        acc1 = __builtin_amdgcn_mfma_f32_16x16x32_f16(Ahh[1], hf1, acc1,   0, 0, 0);
        acc2 = __builtin_amdgcn_mfma_f32_16x16x32_f16(Ahh[3], hf3, acc2,   0, 0, 0);

        const int nb = (t + 1) & 1;
        {
            half2v p; p[0] = (_Float16)rx0[0]; p[1] = (_Float16)rx0[1];
            *(half2v*)(xbuf + nb * 2048 + xoff_lds(bx, kx >> 3, (kx & 7) * 2)) = p;
        }
        rx0 = rx1; rx1 = rx2;
        rx2 = *(const f32x2*)xload;
        if (t + 5 < SEQ) xload += XSTEP;

        f32x4 hv;
        #pragma unroll
        for (int r = 0; r < 4; ++r) hv[r] = fast_tanh(acc1[r] + acc2[r]);
        {
            half4v p;
            #pragma unroll
            for (int r = 0; r < 4; ++r) p[r] = (_Float16)hv[r];
            *(half4v*)(hbuf + nb * 4096 + hoffc(lb, (wave << 1) + (lg >> 1), (lg & 1) * 8)) = p;
        }

        asm volatile("s_waitcnt lgkmcnt(0)" ::: "memory");
        __builtin_amdgcn_s_barrier();
        asm volatile("" ::: "memory");

        hf0 = *(const half8*)(hbuf + nb * 4096 + hoffc(lb, 0 * 4 + lg, 0));
        hf2 = *(const half8*)(hbuf + nb * 4096 + hoffc(lb, 2 * 4 + lg, 0));
        hf1 = *(const half8*)(hbuf + nb * 4096 + hoffc(lb, 1 * 4 + lg, 0));
        hf3 = *(const half8*)(hbuf + nb * 4096 + hoffc(lb, 3 * 4 + lg, 0));
        xf0 = *(const half8*)(xbuf + nb * 2048 + xoff_lds(lb, 0 * 4 + lg, 0));
        xf1 = *(const half8*)(xbuf + nb * 2048 + xoff_lds(lb, 1 * 4 + lg, 0));

        acc_ih = __builtin_amdgcn_mfma_f32_16x16x32_f16(Aih[0], xf0, bias,   0, 0, 0);
        acc_ih = __builtin_amdgcn_mfma_f32_16x16x32_f16(Aih[1], xf1, acc_ih, 0, 0, 0);
    }

    {
        f32x4 zz = {0.0f, 0.0f, 0.0f, 0.0f};
        f32x4 acc1, acc2;
        acc1 = __builtin_amdgcn_mfma_f32_16x16x32_f16(Ahh[0], hf0, acc_ih, 0, 0, 0);
        acc2 = __builtin_amdgcn_mfma_f32_16x16x32_f16(Ahh[2], hf2, zz,     0, 0, 0);
        acc1 = __builtin_amdgcn_mfma_f32_16x16x32_f16(Ahh[1], hf1, acc1,   0, 0, 0);
        acc2 = __builtin_amdgcn_mfma_f32_16x16x32_f16(Ahh[3], hf3, acc2,   0, 0, 0);
        f32x4 res;
        #pragma unroll
        for (int r = 0; r < 4; ++r) res[r] = fast_tanh(acc1[r] + acc2[r]);
        *(f32x4*)(out + (size_t)(bbase + lb) * DH + jbase + (lg << 2)) = res;
    }
}

extern "C" void kernel_launch(void* const* d_in, const int* in_sizes, int n_in,
                              void* d_out, int out_size, void* d_ws, size_t ws_size,
                              hipStream_t stream) {
    const float* x   = (const float*)d_in[0];
    const float* Wih = (const float*)d_in[1];
    const float* bih = (const float*)d_in[2];
    const float* Whh = (const float*)d_in[3];
    const float* bhh = (const float*)d_in[4];
    float* out = (float*)d_out;

    const size_t need = (size_t)SEQ * BATCH * DH * sizeof(_Float16);  // 256 MB
    if (ws_size >= need) {
        _Float16* xp = (_Float16*)d_ws;
        rnn_prepass<<<SEQ * BATCH / 64, 256, 0, stream>>>(x, Wih, bih, bhh, xp);
        rnn_scan_xp<<<16, 512, 0, stream>>>(xp, Whh, out);
    } else {
        rnn_fused_scan_r2<<<16, 512, 0, stream>>>(x, Wih, bih, Whh, bhh, out);
    }
}